// Round 1
// baseline (340.309 us; speedup 1.0000x reference)
//
#include <hip/hip_runtime.h>

// GR4J production-store scan, parallelized by contraction:
// the per-step map s -> f(s) has |f'| ~= 1 - 0.012, so a chunk's true state
// is recovered by WARMUP steps of warm-up from an arbitrary guess.
// L_CHUNK=128, WARMUP=2048: guess error 350 * e^-24.6 ~= 7e-9 < fp32 ulp(165).

#define L_CHUNK 128
#define WARMUP  2048

struct StepConsts { float x1, inv_x1, c49; };

// 1/(1+a) for |a| <= ~0.03 ; relative error ~ a^4 <= 7e-7
__device__ __forceinline__ float inv1p(float a) {
    float i1 = 1.0f - a;
    float i2 = fmaf(-a, i1, 1.0f);
    return fmaf(-a, i2, 1.0f);
}

__device__ __forceinline__ void scan_step(float& s, float P, float E, const StepConsts c,
                                          float& pn, float& en, float& ps, float& pc) {
    float d   = P - E;
    float pn_ = fmaxf(d, 0.0f);
    float en_ = fmaxf(-d, 0.0f);
    // tanh(u) = u*(1 - u^2/3), u <= 10/350 = 0.0286 -> rel err ~9e-8
    float up = pn_ * c.inv_x1;
    float tp = up * fmaf(up * up, -(1.0f / 3.0f), 1.0f);
    float un = en_ * c.inv_x1;
    float tn = un * fmaf(un * un, -(1.0f / 3.0f), 1.0f);
    float tpx1 = tp * c.x1;

    float r   = s * c.inv_x1;
    float a   = r * tp;
    float num = tpx1 * fmaf(-r, r, 1.0f);        // x1*tp*(1-r^2)
    float ps_ = num * inv1p(a);                  // p_s

    float dd    = (1.0f - r) * tn;
    float e_num = (s * (2.0f - r)) * tn;
    float es_   = e_num * inv1p(dd);             // e_s

    float s1 = s + ps_ - es_;
    // (1+v)^(-1/4) ~= 1 - v/4 + (5/32)v^2 ; on-trajectory v ~ 2e-3 -> err ~8e-10
    float z  = s1 * c.c49;                       // (4/9)*s/x1
    float z2 = z * z;
    float v  = z2 * z2;
    float t  = fmaf(v, fmaf(v, 0.15625f, -0.25f), 1.0f);
    float s2 = s1 * t;

    pn = pn_; en = en_; ps = ps_; pc = s1 - s2;  // perc = s1 - s2
    s = s2;
}

__global__ __launch_bounds__(256) void scan_kernel(
        const float* __restrict__ x, const float* __restrict__ x1ptr,
        float* __restrict__ out, float* __restrict__ s_store,
        float* __restrict__ partials, int T) {
    const int c = blockIdx.x * blockDim.x + threadIdx.x;
    const int nchunks = (T + L_CHUNK - 1) / L_CHUNK;

    StepConsts cc;
    cc.x1     = x1ptr[0];
    cc.inv_x1 = 1.0f / cc.x1;
    cc.c49    = (4.0f / 9.0f) * cc.inv_x1;

    float s1a[4] = {0.f, 0.f, 0.f, 0.f};
    float s2a[4] = {0.f, 0.f, 0.f, 0.f};

    if (c < nchunks) {
        const int g0 = c * L_CHUNK;
        const int g1 = min(g0 + L_CHUNK, T);
        const int w0 = max(g0 - WARMUP, 0);      // clamped -> early chunks exact
        const float4* __restrict__ x4 = (const float4*)x; // x4[i] = {P,E,P,E} of t=2i,2i+1
        const int imax = (T >> 1) - 2;

        float s = 0.0f;
        float pn, en, ps, pc;

        // ---- warm-up [w0, g0) : lengths are multiples of 4 ----
        {
            int i = w0 >> 1;
            const int iw = g0 >> 1;
            if (i < iw) {
                float4 a = x4[i];
                float4 b = x4[i + 1];
                for (; i < iw; i += 2) {
                    const int ip = min(i + 2, imax);   // prefetch next 4 steps
                    float4 an = x4[ip];
                    float4 bn = x4[ip + 1];
                    scan_step(s, a.x, a.y, cc, pn, en, ps, pc);
                    scan_step(s, a.z, a.w, cc, pn, en, ps, pc);
                    scan_step(s, b.x, b.y, cc, pn, en, ps, pc);
                    scan_step(s, b.z, b.w, cc, pn, en, ps, pc);
                    a = an; b = bn;
                }
            }
        }

        // ---- main [g0, g1) : store rows + accumulate column stats ----
        float4* __restrict__ out4 = (float4*)out;
        auto emit = [&](float P, float E, int tt) {
            scan_step(s, P, E, cc, pn, en, ps, pc);
            out4[tt] = make_float4(pn, en, ps, pc);
            s_store[tt] = s;
            s1a[0] += pn; s1a[1] += en; s1a[2] += ps; s1a[3] += pc;
            s2a[0] = fmaf(pn, pn, s2a[0]); s2a[1] = fmaf(en, en, s2a[1]);
            s2a[2] = fmaf(ps, ps, s2a[2]); s2a[3] = fmaf(pc, pc, s2a[3]);
        };

        int t = g0;
        if (t + 4 <= g1) {
            int j = t >> 1;
            float4 a = x4[j];
            float4 b = x4[j + 1];
            for (; t + 4 <= g1; t += 4, j += 2) {
                const int jp = min(j + 2, imax);
                float4 an = x4[jp];
                float4 bn = x4[jp + 1];
                emit(a.x, a.y, t);
                emit(a.z, a.w, t + 1);
                emit(b.x, b.y, t + 2);
                emit(b.z, b.w, t + 3);
                a = an; b = bn;
            }
        }
        const float2* __restrict__ x2 = (const float2*)x;
        for (; t < g1; ++t) {                     // generic tail (unused at T=2^21)
            float2 xv = x2[t];
            emit(xv.x, xv.y, t);
        }
    }

    // ---- deterministic block reduction of the 8 stat accumulators ----
    __shared__ float red[256];
    float vals[8] = {s1a[0], s1a[1], s1a[2], s1a[3], s2a[0], s2a[1], s2a[2], s2a[3]};
    for (int k = 0; k < 8; ++k) {
        red[threadIdx.x] = vals[k];
        __syncthreads();
        for (int off = 128; off > 0; off >>= 1) {
            if ((int)threadIdx.x < off) red[threadIdx.x] += red[threadIdx.x + off];
            __syncthreads();
        }
        if (threadIdx.x == 0) partials[blockIdx.x * 8 + k] = red[0];
        __syncthreads();
    }
}

__global__ __launch_bounds__(64) void finalize_stats(
        const float* __restrict__ partials, float* __restrict__ stats,
        int nblk, int T) {
    const int lane = threadIdx.x;
    float v[8] = {0.f, 0.f, 0.f, 0.f, 0.f, 0.f, 0.f, 0.f};
    for (int b = lane; b < nblk; b += 64) {
        #pragma unroll
        for (int k = 0; k < 8; ++k) v[k] += partials[b * 8 + k];
    }
    #pragma unroll
    for (int k = 0; k < 8; ++k) {
        #pragma unroll
        for (int off = 32; off > 0; off >>= 1) v[k] += __shfl_down(v[k], off, 64);
    }
    if (lane == 0) {
        const float invT = 1.0f / (float)T;
        #pragma unroll
        for (int k = 0; k < 4; ++k) {
            float mu  = v[k] * invT;
            float var = fmaxf(fmaf(-mu, mu, v[k + 4] * invT), 0.0f);
            stats[k]     = mu;
            stats[4 + k] = (var > 0.0f) ? rsqrtf(var) : 0.0f;   // 1/sigma
        }
    }
}

__global__ __launch_bounds__(256) void normalize_kernel(
        float* __restrict__ out, const float* __restrict__ stats, int T) {
    const int t = blockIdx.x * blockDim.x + threadIdx.x;
    if (t >= T) return;
    const float4 mu = *(const float4*)stats;
    const float4 is = *(const float4*)(stats + 4);
    float4* o4 = (float4*)out;
    float4 v = o4[t];
    v.x = (v.x - mu.x) * is.x;
    v.y = (v.y - mu.y) * is.y;
    v.z = (v.z - mu.z) * is.z;
    v.w = (v.w - mu.w) * is.w;
    o4[t] = v;
}

extern "C" void kernel_launch(void* const* d_in, const int* in_sizes, int n_in,
                              void* d_out, int out_size, void* d_ws, size_t ws_size,
                              hipStream_t stream) {
    const float* x  = (const float*)d_in[0];
    const float* x1 = (const float*)d_in[1];
    const int T = in_sizes[0] / 2;

    float* out     = (float*)d_out;                    // (T,4) row-major
    float* s_store = out + 4 * (size_t)T;              // (T,)
    float* stats    = (float*)d_ws;                    // mu[4], inv_sigma[4]
    float* partials = stats + 8;                       // nblkA * 8

    const int nchunks = (T + L_CHUNK - 1) / L_CHUNK;
    const int nblkA   = (nchunks + 255) / 256;

    scan_kernel<<<nblkA, 256, 0, stream>>>(x, x1, out, s_store, partials, T);
    finalize_stats<<<1, 64, 0, stream>>>(partials, stats, nblkA, T);
    const int nblkC = (T + 255) / 256;
    normalize_kernel<<<nblkC, 256, 0, stream>>>(out, stats, T);
}

// Round 2
// 283.259 us; speedup vs baseline: 1.2014x; 1.2014x over previous
//
#include <hip/hip_runtime.h>

// GR4J production-store scan, parallelized by contraction (W warm-up steps
// recover the chunk-entry state; measured decay rate delta ~ 0.0029/step ->
// W=2048 gives |err| ~ 1.0 absolute on s, passed with threshold 4.82).
//
// Round-2 structure:
//   featurize: precompute s-independent features (x1*tp, tp/x1, tn, tn/x1)
//              in a TRANSPOSED layout G[(tau % L)*Cp + tau/L], front-padded
//              with W rows of zeros (zero features keep s at 0 == clamped
//              warm-up, so early chunks stay exact).
//   scan_fast: 1 chunk/thread, 23-VALU-op step, coalesced float4 loads with
//              linear stride Cp*16B, 8-deep prefetch. 256 blocks x 64.
//   finalize + normalize: unchanged.
// Fallback to the round-1 kernel if ws_size is too small for G.

#define L_CHUNK 128
#define WARMUP  2048

struct StepConsts { float x1, inv_x1, c49; };

// 1/(1+a) for |a| <= ~0.03 ; relative error ~ a^4 <= 7e-7
__device__ __forceinline__ float inv1p(float a) {
    float i1 = 1.0f - a;
    float i2 = fmaf(-a, i1, 1.0f);
    return fmaf(-a, i2, 1.0f);
}

// f = (tpx1, tp_ox1, tn, tn_ox1)
__device__ __forceinline__ void step_s(float& s, const float4 f, const StepConsts c) {
    float r  = s * c.inv_x1;
    float a  = s * f.y;                       // r*tp
    float i3 = inv1p(a);
    float num = f.x * fmaf(-r, r, 1.0f);      // x1*tp*(1-r^2)
    float ps  = num * i3;
    float dd  = fmaf(-s, f.w, f.z);           // (1-r)*tn
    float j3  = inv1p(dd);
    float es  = (s * (f.z + dd)) * j3;        // s*(2-r)*tn/(1+(1-r)tn)
    float s1  = s + ps - es;
    float z = s1 * c.c49, z2 = z * z, v = z2 * z2;
    float tt = fmaf(v, fmaf(v, 0.15625f, -0.25f), 1.0f); // (1+v)^-0.25
    s = s1 * tt;
}

__device__ __forceinline__ void step_full(float& s, const float4 f, const StepConsts c,
                                          float& ps_o, float& pc_o) {
    float r  = s * c.inv_x1;
    float a  = s * f.y;
    float i3 = inv1p(a);
    float num = f.x * fmaf(-r, r, 1.0f);
    float ps  = num * i3;
    float dd  = fmaf(-s, f.w, f.z);
    float j3  = inv1p(dd);
    float es  = (s * (f.z + dd)) * j3;
    float s1  = s + ps - es;
    float z = s1 * c.c49, z2 = z * z, v = z2 * z2;
    float tt = fmaf(v, fmaf(v, 0.15625f, -0.25f), 1.0f);
    float s2 = s1 * tt;
    ps_o = ps; pc_o = s1 - s2; s = s2;
}

__global__ __launch_bounds__(256) void featurize(
        const float* __restrict__ x, const float* __restrict__ x1p,
        float4* __restrict__ Gp, int T, int Cp) {
    const int colp = blockIdx.x * 256 + threadIdx.x;
    const int row  = blockIdx.y;
    if (colp >= Cp) return;
    const float x1 = x1p[0];
    const float inv = 1.0f / x1;
    const int tau = colp * L_CHUNK + row;          // virtual time, t = tau - W
    float4 f = make_float4(0.f, 0.f, 0.f, 0.f);
    if (tau >= WARMUP) {
        const float2 xv = ((const float2*)x)[tau - WARMUP];
        float d  = xv.x - xv.y;
        float pn = fmaxf(d, 0.0f);
        float en = fmaxf(-d, 0.0f);
        float up = pn * inv;
        float tp = up * fmaf(up * up, -(1.0f / 3.0f), 1.0f);
        float un = en * inv;
        float tn = un * fmaf(un * un, -(1.0f / 3.0f), 1.0f);
        f = make_float4(tp * x1, tp * inv, tn, tn * inv);
    }
    Gp[(size_t)row * Cp + colp] = f;
}

__global__ __launch_bounds__(64) void scan_fast(
        const float4* __restrict__ Gp, const float4* __restrict__ x4,
        const float* __restrict__ x1p,
        float4* __restrict__ out4, float* __restrict__ s_store,
        float* __restrict__ partials, int T, int Cp) {
    const int c = blockIdx.x * 64 + threadIdx.x;   // chunk id, exact grid
    StepConsts cc;
    cc.x1 = x1p[0]; cc.inv_x1 = 1.0f / cc.x1; cc.c49 = (4.0f / 9.0f) * cc.inv_x1;
    const size_t cp = (size_t)Cp;
    float s = 0.0f;

    // ---- warm-up: k = j*L + m, Gp index = m*Cp + (c + j) ----
    for (int j = 0; j < WARMUP / L_CHUNK; ++j) {
        const float4* p = Gp + (size_t)c + j;
        float4 f[8];
        #pragma unroll
        for (int u = 0; u < 8; ++u) f[u] = p[u * cp];
        p += 8 * cp;
        for (int m = 0; m < L_CHUNK; m += 8) {
            float4 g[8];
            #pragma unroll
            for (int u = 0; u < 8; ++u) g[u] = p[u * cp];   // rows m+8..m+15 (pad rows at end)
            p += 8 * cp;
            #pragma unroll
            for (int u = 0; u < 8; ++u) step_s(s, f[u], cc);
            #pragma unroll
            for (int u = 0; u < 8; ++u) f[u] = g[u];
        }
    }

    // ---- main segment: t = c*L + m, Gp index = m*Cp + (c + W/L) ----
    float s1a[4] = {0.f, 0.f, 0.f, 0.f};
    float s2a[4] = {0.f, 0.f, 0.f, 0.f};
    {
        const float4* p = Gp + (size_t)c + (WARMUP / L_CHUNK);
        const size_t xbase = (size_t)c * (L_CHUNK / 2);   // float4 pair index
        const size_t xmax  = (size_t)(T / 2) - 4;
        const size_t t0 = (size_t)c * L_CHUNK;

        float4 f[8], xx[4];
        #pragma unroll
        for (int u = 0; u < 8; ++u) f[u] = p[u * cp];
        p += 8 * cp;
        #pragma unroll
        for (int q = 0; q < 4; ++q) xx[q] = x4[xbase + q];

        for (int m = 0; m < L_CHUNK; m += 8) {
            float4 g[8], yy[4];
            #pragma unroll
            for (int u = 0; u < 8; ++u) g[u] = p[u * cp];
            p += 8 * cp;
            const size_t xb = (xbase + (size_t)(m / 2) + 4 < xmax) ? (xbase + (size_t)(m / 2) + 4) : xmax;
            #pragma unroll
            for (int q = 0; q < 4; ++q) yy[q] = x4[xb + q];

            #pragma unroll
            for (int u = 0; u < 8; ++u) {
                float P = (u & 1) ? xx[u >> 1].z : xx[u >> 1].x;
                float E = (u & 1) ? xx[u >> 1].w : xx[u >> 1].y;
                float d  = P - E;
                float pn = fmaxf(d, 0.0f);
                float en = fmaxf(-d, 0.0f);
                float ps, pc;
                step_full(s, f[u], cc, ps, pc);
                const size_t tt = t0 + m + u;
                out4[tt] = make_float4(pn, en, ps, pc);
                s_store[tt] = s;
                s1a[0] += pn; s1a[1] += en; s1a[2] += ps; s1a[3] += pc;
                s2a[0] = fmaf(pn, pn, s2a[0]); s2a[1] = fmaf(en, en, s2a[1]);
                s2a[2] = fmaf(ps, ps, s2a[2]); s2a[3] = fmaf(pc, pc, s2a[3]);
            }
            #pragma unroll
            for (int u = 0; u < 8; ++u) f[u] = g[u];
            #pragma unroll
            for (int q = 0; q < 4; ++q) xx[q] = yy[q];
        }
    }

    // ---- block == one wave: shuffle reduction, deterministic ----
    float vals[8] = {s1a[0], s1a[1], s1a[2], s1a[3], s2a[0], s2a[1], s2a[2], s2a[3]};
    #pragma unroll
    for (int k = 0; k < 8; ++k) {
        float v = vals[k];
        #pragma unroll
        for (int off = 32; off > 0; off >>= 1) v += __shfl_down(v, off, 64);
        if (threadIdx.x == 0) partials[blockIdx.x * 8 + k] = v;
    }
}

// ---------------- round-1 fallback scan (used if ws too small) ----------------
__device__ __forceinline__ void scan_step_fb(float& s, float P, float E, const StepConsts c,
                                             float& pn, float& en, float& ps, float& pc) {
    float d   = P - E;
    float pn_ = fmaxf(d, 0.0f);
    float en_ = fmaxf(-d, 0.0f);
    float up = pn_ * c.inv_x1;
    float tp = up * fmaf(up * up, -(1.0f / 3.0f), 1.0f);
    float un = en_ * c.inv_x1;
    float tn = un * fmaf(un * un, -(1.0f / 3.0f), 1.0f);
    float tpx1 = tp * c.x1;
    float r   = s * c.inv_x1;
    float a   = r * tp;
    float num = tpx1 * fmaf(-r, r, 1.0f);
    float ps_ = num * inv1p(a);
    float dd    = (1.0f - r) * tn;
    float e_num = (s * (2.0f - r)) * tn;
    float es_   = e_num * inv1p(dd);
    float s1 = s + ps_ - es_;
    float z  = s1 * c.c49;
    float z2 = z * z;
    float v  = z2 * z2;
    float t  = fmaf(v, fmaf(v, 0.15625f, -0.25f), 1.0f);
    float s2 = s1 * t;
    pn = pn_; en = en_; ps = ps_; pc = s1 - s2;
    s = s2;
}

__global__ __launch_bounds__(256) void scan_kernel_fb(
        const float* __restrict__ x, const float* __restrict__ x1ptr,
        float* __restrict__ out, float* __restrict__ s_store,
        float* __restrict__ partials, int T) {
    const int c = blockIdx.x * blockDim.x + threadIdx.x;
    const int nchunks = (T + L_CHUNK - 1) / L_CHUNK;
    StepConsts cc;
    cc.x1 = x1ptr[0]; cc.inv_x1 = 1.0f / cc.x1; cc.c49 = (4.0f / 9.0f) * cc.inv_x1;
    float s1a[4] = {0.f, 0.f, 0.f, 0.f};
    float s2a[4] = {0.f, 0.f, 0.f, 0.f};
    if (c < nchunks) {
        const int g0 = c * L_CHUNK;
        const int g1 = min(g0 + L_CHUNK, T);
        const int w0 = max(g0 - WARMUP, 0);
        const float4* __restrict__ x4 = (const float4*)x;
        const int imax = (T >> 1) - 2;
        float s = 0.0f;
        float pn, en, ps, pc;
        {
            int i = w0 >> 1;
            const int iw = g0 >> 1;
            if (i < iw) {
                float4 a = x4[i];
                float4 b = x4[i + 1];
                for (; i < iw; i += 2) {
                    const int ip = min(i + 2, imax);
                    float4 an = x4[ip];
                    float4 bn = x4[ip + 1];
                    scan_step_fb(s, a.x, a.y, cc, pn, en, ps, pc);
                    scan_step_fb(s, a.z, a.w, cc, pn, en, ps, pc);
                    scan_step_fb(s, b.x, b.y, cc, pn, en, ps, pc);
                    scan_step_fb(s, b.z, b.w, cc, pn, en, ps, pc);
                    a = an; b = bn;
                }
            }
        }
        float4* __restrict__ out4 = (float4*)out;
        auto emit = [&](float P, float E, int tt) {
            scan_step_fb(s, P, E, cc, pn, en, ps, pc);
            out4[tt] = make_float4(pn, en, ps, pc);
            s_store[tt] = s;
            s1a[0] += pn; s1a[1] += en; s1a[2] += ps; s1a[3] += pc;
            s2a[0] = fmaf(pn, pn, s2a[0]); s2a[1] = fmaf(en, en, s2a[1]);
            s2a[2] = fmaf(ps, ps, s2a[2]); s2a[3] = fmaf(pc, pc, s2a[3]);
        };
        int t = g0;
        if (t + 4 <= g1) {
            int j = t >> 1;
            float4 a = x4[j];
            float4 b = x4[j + 1];
            for (; t + 4 <= g1; t += 4, j += 2) {
                const int jp = min(j + 2, imax);
                float4 an = x4[jp];
                float4 bn = x4[jp + 1];
                emit(a.x, a.y, t);
                emit(a.z, a.w, t + 1);
                emit(b.x, b.y, t + 2);
                emit(b.z, b.w, t + 3);
                a = an; b = bn;
            }
        }
        const float2* __restrict__ x2 = (const float2*)x;
        for (; t < g1; ++t) { float2 xv = x2[t]; emit(xv.x, xv.y, t); }
    }
    __shared__ float red[256];
    float vals[8] = {s1a[0], s1a[1], s1a[2], s1a[3], s2a[0], s2a[1], s2a[2], s2a[3]};
    for (int k = 0; k < 8; ++k) {
        red[threadIdx.x] = vals[k];
        __syncthreads();
        for (int off = 128; off > 0; off >>= 1) {
            if ((int)threadIdx.x < off) red[threadIdx.x] += red[threadIdx.x + off];
            __syncthreads();
        }
        if (threadIdx.x == 0) partials[blockIdx.x * 8 + k] = red[0];
        __syncthreads();
    }
}
// -----------------------------------------------------------------------------

__global__ __launch_bounds__(64) void finalize_stats(
        const float* __restrict__ partials, float* __restrict__ stats,
        int nblk, int T) {
    const int lane = threadIdx.x;
    float v[8] = {0.f, 0.f, 0.f, 0.f, 0.f, 0.f, 0.f, 0.f};
    for (int b = lane; b < nblk; b += 64) {
        #pragma unroll
        for (int k = 0; k < 8; ++k) v[k] += partials[b * 8 + k];
    }
    #pragma unroll
    for (int k = 0; k < 8; ++k) {
        #pragma unroll
        for (int off = 32; off > 0; off >>= 1) v[k] += __shfl_down(v[k], off, 64);
    }
    if (lane == 0) {
        const float invT = 1.0f / (float)T;
        #pragma unroll
        for (int k = 0; k < 4; ++k) {
            float mu  = v[k] * invT;
            float var = fmaxf(fmaf(-mu, mu, v[k + 4] * invT), 0.0f);
            stats[k]     = mu;
            stats[4 + k] = (var > 0.0f) ? rsqrtf(var) : 0.0f;   // 1/sigma
        }
    }
}

__global__ __launch_bounds__(256) void normalize_kernel(
        float* __restrict__ out, const float* __restrict__ stats, int T) {
    const int t = blockIdx.x * blockDim.x + threadIdx.x;
    if (t >= T) return;
    const float4 mu = *(const float4*)stats;
    const float4 is = *(const float4*)(stats + 4);
    float4* o4 = (float4*)out;
    float4 v = o4[t];
    v.x = (v.x - mu.x) * is.x;
    v.y = (v.y - mu.y) * is.y;
    v.z = (v.z - mu.z) * is.z;
    v.w = (v.w - mu.w) * is.w;
    o4[t] = v;
}

extern "C" void kernel_launch(void* const* d_in, const int* in_sizes, int n_in,
                              void* d_out, int out_size, void* d_ws, size_t ws_size,
                              hipStream_t stream) {
    const float* x  = (const float*)d_in[0];
    const float* x1 = (const float*)d_in[1];
    const int T = in_sizes[0] / 2;

    float* out     = (float*)d_out;                    // (T,4) row-major
    float* s_store = out + 4 * (size_t)T;              // (T,)
    float* stats    = (float*)d_ws;                    // mu[4], inv_sigma[4]
    float* partials = stats + 8;                       // up to 256*8

    const int C  = T / L_CHUNK;
    const int Cp = C + WARMUP / L_CHUNK;
    const size_t gp_off_floats = 2112;                 // 16B-aligned offset past stats+partials
    const size_t gp_floats = (size_t)(L_CHUNK + 8) * (size_t)Cp * 4;  // +8 pad rows for prefetch overrun
    const size_t need_bytes = (gp_off_floats + gp_floats) * sizeof(float);

    const bool fast = (T % L_CHUNK == 0) && (C % 64 == 0) &&
                      (WARMUP % L_CHUNK == 0) && (ws_size >= need_bytes);

    if (fast) {
        float4* Gp = (float4*)(stats + gp_off_floats);
        dim3 fgrid((Cp + 255) / 256, L_CHUNK);
        featurize<<<fgrid, 256, 0, stream>>>(x, x1, Gp, T, Cp);
        const int nblk = C / 64;                       // 256 blocks of 64 (1 wave each)
        scan_fast<<<nblk, 64, 0, stream>>>(Gp, (const float4*)x, x1,
                                           (float4*)out, s_store, partials, T, Cp);
        finalize_stats<<<1, 64, 0, stream>>>(partials, stats, nblk, T);
    } else {
        const int nchunks = (T + L_CHUNK - 1) / L_CHUNK;
        const int nblkA   = (nchunks + 255) / 256;
        scan_kernel_fb<<<nblkA, 256, 0, stream>>>(x, x1, out, s_store, partials, T);
        finalize_stats<<<1, 64, 0, stream>>>(partials, stats, nblkA, T);
    }
    const int nblkC = (T + 255) / 256;
    normalize_kernel<<<nblkC, 256, 0, stream>>>(out, stats, T);
}

// Round 3
// 235.250 us; speedup vs baseline: 1.4466x; 1.2041x over previous
//
#include <hip/hip_runtime.h>

// GR4J production-store scan, parallelized by contraction (W=2048 warm-up
// steps recover chunk-entry state; measured absmax 1.0 vs threshold 4.82).
//
// Round-3: async global->LDS ring pipeline for the feature stream.
//   featurize2 : (tp/x1, tn/x1) per step, transposed row-pair layout
//                G4[rp*Cp + col] = (tpx_2rp, tnx_2rp, tpx_2rp+1, tnx_2rp+1),
//                16 front pad columns of zeros; also reduces pn/en stats.
//   scan_pipe  : 1 chunk/thread, 64-thread (1-wave) blocks, 8-slot x 4KB LDS
//                ring fed by global_load_lds (16B/lane), prefetch distance 6
//                stages, manual s_waitcnt vmcnt(24) (no __syncthreads -> no
//                vmcnt(0) drain). 19-op step. Emits compact (ps,pc)+s only.
//   finalize_comb + normalize_fused : stats merge, pn/en recomputed from x.
// Fallback to the round-1 kernel if ws_size too small / odd shapes.

#define L_CHUNK 128
#define WARMUP  2048
#define W_TILES (WARMUP / L_CHUNK)            // 16
#define N_STAGE ((WARMUP + L_CHUNK) / 8)      // 272 stages of 8 steps
#define WU_STAGE (WARMUP / 8)                 // 256 warm-up stages
#define PF_DIST 6                             // prefetch distance (stages)
#define WAITVM(N) (((N) & 15) | (7 << 4) | (15 << 8) | (((N) >> 4) << 14))

typedef const __attribute__((address_space(1))) void* as1_cvp;
typedef __attribute__((address_space(3))) void*       as3_vp;

struct SC { float x1, x1sq, x1_2, c49; };

// one step from precomputed (tpx = tp/x1, tnx = tn/x1); 19 VALU ops
__device__ __forceinline__ void step1(float& s, float tpx, float tnx, const SC c) {
    float a   = s * tpx;                         // r*tp
    float i   = fmaf(a, a - 1.0f, 1.0f);         // ~1/(1+a), 2nd order
    float num = tpx * fmaf(-s, s, c.x1sq);       // x1*tp*(1-r^2)
    float w   = c.x1 - s;
    float dd  = tnx * w;                         // (1-r)*tn
    float jj  = fmaf(dd, dd - 1.0f, 1.0f);       // ~1/(1+dd)
    float mm  = (s * tnx) * (c.x1_2 - s);        // s*(2-r)*tn
    float t1  = fmaf(num, i, s);                 // s + p_s
    float s1  = fmaf(-mm, jj, t1);               // s + p_s - e_s
    float z = s1 * c.c49, z2 = z * z, v = z2 * z2;
    float th = fmaf(v, fmaf(v, 0.15625f, -0.25f), 1.0f);  // (1+v)^-1/4
    s = s1 * th;
}

__device__ __forceinline__ void stepm(float& s, float tpx, float tnx, const SC c,
                                      float& ps_o, float& pc_o) {
    float a   = s * tpx;
    float i   = fmaf(a, a - 1.0f, 1.0f);
    float num = tpx * fmaf(-s, s, c.x1sq);
    float w   = c.x1 - s;
    float dd  = tnx * w;
    float jj  = fmaf(dd, dd - 1.0f, 1.0f);
    float mm  = (s * tnx) * (c.x1_2 - s);
    float t1  = fmaf(num, i, s);
    float s1  = fmaf(-mm, jj, t1);
    float z = s1 * c.c49, z2 = z * z, v = z2 * z2;
    float th = fmaf(v, fmaf(v, 0.15625f, -0.25f), 1.0f);
    float s2 = s1 * th;
    ps_o = num * i;
    pc_o = s1 - s2;
    s = s2;
}

// ---- featurize: transposed (tpx,tnx) pairs + pn/en stats ----
__global__ __launch_bounds__(256) void featurize2(
        const float* __restrict__ x, const float* __restrict__ x1p,
        float4* __restrict__ G4, float* __restrict__ partialsB, int Cp, int T) {
    const int col = blockIdx.x * 256 + threadIdx.x;
    const int rp0 = blockIdx.y * 16;
    const float x1 = x1p[0];
    const float inv = 1.0f / x1;
    float spn = 0.f, sen = 0.f, qpn = 0.f, qen = 0.f;
    if (col < Cp) {
        if (col < W_TILES) {
            const float4 z = make_float4(0.f, 0.f, 0.f, 0.f);
            for (int q = 0; q < 16; ++q) G4[(size_t)(rp0 + q) * Cp + col] = z;
        } else {
            const float4* __restrict__ x4 = (const float4*)x;
            const size_t xb = (size_t)(col - W_TILES) * 64;
            for (int q = 0; q < 16; ++q) {
                float4 xv = x4[xb + rp0 + q];          // (P,E,P,E) of 2 steps
                float d0 = xv.x - xv.y, d1 = xv.z - xv.w;
                float pn0 = fmaxf(d0, 0.f), en0 = fmaxf(-d0, 0.f);
                float pn1 = fmaxf(d1, 0.f), en1 = fmaxf(-d1, 0.f);
                float u0 = pn0 * inv, v0 = en0 * inv;
                float u1 = pn1 * inv, v1 = en1 * inv;
                float tpx0 = (u0 * fmaf(u0 * u0, -(1.f/3.f), 1.f)) * inv;
                float tnx0 = (v0 * fmaf(v0 * v0, -(1.f/3.f), 1.f)) * inv;
                float tpx1 = (u1 * fmaf(u1 * u1, -(1.f/3.f), 1.f)) * inv;
                float tnx1 = (v1 * fmaf(v1 * v1, -(1.f/3.f), 1.f)) * inv;
                G4[(size_t)(rp0 + q) * Cp + col] = make_float4(tpx0, tnx0, tpx1, tnx1);
                spn += pn0 + pn1; sen += en0 + en1;
                qpn = fmaf(pn0, pn0, fmaf(pn1, pn1, qpn));
                qen = fmaf(en0, en0, fmaf(en1, en1, qen));
            }
        }
    }
    __shared__ float red[256];
    float vals[4] = {spn, sen, qpn, qen};
    const int bid = blockIdx.y * gridDim.x + blockIdx.x;
    for (int k = 0; k < 4; ++k) {
        red[threadIdx.x] = vals[k];
        __syncthreads();
        for (int off = 128; off > 0; off >>= 1) {
            if ((int)threadIdx.x < off) red[threadIdx.x] += red[threadIdx.x + off];
            __syncthreads();
        }
        if (threadIdx.x == 0) partialsB[bid * 4 + k] = red[0];
        __syncthreads();
    }
}

// ---- the pipelined scan ----
__global__ __launch_bounds__(64, 1) void scan_pipe(
        const float4* __restrict__ G4, const float* __restrict__ x1p,
        float4* __restrict__ pspc4, float4* __restrict__ s4,
        float* __restrict__ partialsA, int Cp) {
    __shared__ float4 ring[8 * 256];               // 8 slots x 4KB
    const int lane = threadIdx.x;
    const int c0 = blockIdx.x * 64;
    const int chunk = c0 + lane;
    SC cc;
    cc.x1 = x1p[0]; cc.x1sq = cc.x1 * cc.x1; cc.x1_2 = 2.0f * cc.x1;
    cc.c49 = (4.0f / 9.0f) / cc.x1;

    const float4* gbase = G4 + (size_t)c0 + lane;

    auto issue = [&](int st) {
        const int j = st >> 4, sg = st & 15, slot = st & 7;
        const float4* g = gbase + (size_t)(4 * sg) * Cp + j;
        float4* lb = &ring[slot * 256];
        #pragma unroll
        for (int u = 0; u < 4; ++u)
            __builtin_amdgcn_global_load_lds((as1_cvp)(const void*)(g + (size_t)u * Cp),
                                             (as3_vp)(void*)(lb + u * 64), 16, 0, 0);
    };

    #pragma unroll
    for (int p = 0; p < PF_DIST; ++p) issue(p);

    float s = 0.0f;
    // ---- warm-up: 256 stages, no stores ----
    for (int t = 0; t < WU_STAGE; ++t) {
        issue(t + PF_DIST);                        // t+6 <= 261 < 272 always
        __builtin_amdgcn_s_waitcnt(WAITVM(4 * PF_DIST));
        __builtin_amdgcn_sched_barrier(0);
        __builtin_amdgcn_fence(__ATOMIC_ACQUIRE, "workgroup");
        const float4* sl = &ring[(t & 7) * 256 + lane];
        float4 q0 = sl[0], q1 = sl[64], q2 = sl[128], q3 = sl[192];
        step1(s, q0.x, q0.y, cc); step1(s, q0.z, q0.w, cc);
        step1(s, q1.x, q1.y, cc); step1(s, q1.z, q1.w, cc);
        step1(s, q2.x, q2.y, cc); step1(s, q2.z, q2.w, cc);
        step1(s, q3.x, q3.y, cc); step1(s, q3.z, q3.w, cc);
    }
    // ---- main: 16 stages with outputs + stats ----
    float aps = 0.f, apc = 0.f, qps = 0.f, qpc = 0.f;
    for (int t = WU_STAGE; t < N_STAGE; ++t) {
        if (t + PF_DIST < N_STAGE) issue(t + PF_DIST);
        __builtin_amdgcn_s_waitcnt(WAITVM(4 * PF_DIST));   // conservative: safe w/ stores
        __builtin_amdgcn_sched_barrier(0);
        __builtin_amdgcn_fence(__ATOMIC_ACQUIRE, "workgroup");
        const float4* sl = &ring[(t & 7) * 256 + lane];
        float4 q[4] = {sl[0], sl[64], sl[128], sl[192]};
        float psv[8], pcv[8], sv[8];
        #pragma unroll
        for (int u = 0; u < 4; ++u) {
            stepm(s, q[u].x, q[u].y, cc, psv[2*u], pcv[2*u]);     sv[2*u]   = s;
            stepm(s, q[u].z, q[u].w, cc, psv[2*u+1], pcv[2*u+1]); sv[2*u+1] = s;
        }
        #pragma unroll
        for (int u = 0; u < 8; ++u) {
            aps += psv[u]; apc += pcv[u];
            qps = fmaf(psv[u], psv[u], qps); qpc = fmaf(pcv[u], pcv[u], qpc);
        }
        const int mb = t - WU_STAGE;
        const size_t pb = (size_t)chunk * 64 + 4 * mb;
        #pragma unroll
        for (int k = 0; k < 4; ++k)
            pspc4[pb + k] = make_float4(psv[2*k], pcv[2*k], psv[2*k+1], pcv[2*k+1]);
        const size_t sb = (size_t)chunk * 32 + 2 * mb;
        s4[sb]     = make_float4(sv[0], sv[1], sv[2], sv[3]);
        s4[sb + 1] = make_float4(sv[4], sv[5], sv[6], sv[7]);
    }
    // ---- wave reduction (block == 1 wave) ----
    float vals[4] = {aps, apc, qps, qpc};
    #pragma unroll
    for (int k = 0; k < 4; ++k) {
        float v = vals[k];
        #pragma unroll
        for (int off = 32; off > 0; off >>= 1) v += __shfl_down(v, off, 64);
        if (lane == 0) partialsA[blockIdx.x * 4 + k] = v;
    }
}

__global__ __launch_bounds__(64) void finalize_comb(
        const float* __restrict__ pA, const float* __restrict__ pB,
        float* __restrict__ stats, int nA, int nB, int T) {
    const int lane = threadIdx.x;
    float v[8] = {0.f, 0.f, 0.f, 0.f, 0.f, 0.f, 0.f, 0.f};
    for (int b = lane; b < nA; b += 64) {         // scan: ps,pc
        v[2] += pA[b * 4 + 0]; v[3] += pA[b * 4 + 1];
        v[6] += pA[b * 4 + 2]; v[7] += pA[b * 4 + 3];
    }
    for (int b = lane; b < nB; b += 64) {         // featurize: pn,en
        v[0] += pB[b * 4 + 0]; v[1] += pB[b * 4 + 1];
        v[4] += pB[b * 4 + 2]; v[5] += pB[b * 4 + 3];
    }
    #pragma unroll
    for (int k = 0; k < 8; ++k) {
        #pragma unroll
        for (int off = 32; off > 0; off >>= 1) v[k] += __shfl_down(v[k], off, 64);
    }
    if (lane == 0) {
        const float invT = 1.0f / (float)T;
        #pragma unroll
        for (int k = 0; k < 4; ++k) {
            float mu  = v[k] * invT;
            float var = fmaxf(fmaf(-mu, mu, v[k + 4] * invT), 0.0f);
            stats[k]     = mu;
            stats[4 + k] = (var > 0.0f) ? rsqrtf(var) : 0.0f;
        }
    }
}

__global__ __launch_bounds__(256) void normalize_fused(
        const float* __restrict__ x, const float4* __restrict__ pspc4,
        const float* __restrict__ stats, float4* __restrict__ out4, int Thalf) {
    const int i = blockIdx.x * 256 + threadIdx.x;
    if (i >= Thalf) return;
    const float4 mu = ((const float4*)stats)[0];
    const float4 is = ((const float4*)stats)[1];
    float4 xv = ((const float4*)x)[i];
    float4 pq = pspc4[i];
    float d0 = xv.x - xv.y, d1 = xv.z - xv.w;
    out4[2 * i] = make_float4((fmaxf(d0, 0.f) - mu.x) * is.x,
                              (fmaxf(-d0, 0.f) - mu.y) * is.y,
                              (pq.x - mu.z) * is.z,
                              (pq.y - mu.w) * is.w);
    out4[2 * i + 1] = make_float4((fmaxf(d1, 0.f) - mu.x) * is.x,
                                  (fmaxf(-d1, 0.f) - mu.y) * is.y,
                                  (pq.z - mu.z) * is.z,
                                  (pq.w - mu.w) * is.w);
}

// ---------------- round-1 fallback (proven) ----------------
__device__ __forceinline__ float inv1p_fb(float a) {
    float i1 = 1.0f - a;
    float i2 = fmaf(-a, i1, 1.0f);
    return fmaf(-a, i2, 1.0f);
}
struct SCfb { float x1, inv_x1, c49; };
__device__ __forceinline__ void scan_step_fb(float& s, float P, float E, const SCfb c,
                                             float& pn, float& en, float& ps, float& pc) {
    float d = P - E;
    float pn_ = fmaxf(d, 0.0f), en_ = fmaxf(-d, 0.0f);
    float up = pn_ * c.inv_x1;
    float tp = up * fmaf(up * up, -(1.0f / 3.0f), 1.0f);
    float un = en_ * c.inv_x1;
    float tn = un * fmaf(un * un, -(1.0f / 3.0f), 1.0f);
    float r = s * c.inv_x1;
    float ps_ = (tp * c.x1) * fmaf(-r, r, 1.0f) * inv1p_fb(r * tp);
    float es_ = (s * (2.0f - r)) * tn * inv1p_fb((1.0f - r) * tn);
    float s1 = s + ps_ - es_;
    float z = s1 * c.c49, z2 = z * z, v = z2 * z2;
    float t = fmaf(v, fmaf(v, 0.15625f, -0.25f), 1.0f);
    float s2 = s1 * t;
    pn = pn_; en = en_; ps = ps_; pc = s1 - s2; s = s2;
}
__global__ __launch_bounds__(256) void scan_kernel_fb(
        const float* __restrict__ x, const float* __restrict__ x1ptr,
        float* __restrict__ out, float* __restrict__ s_store,
        float* __restrict__ partials, int T) {
    const int c = blockIdx.x * blockDim.x + threadIdx.x;
    const int nchunks = (T + L_CHUNK - 1) / L_CHUNK;
    SCfb cc; cc.x1 = x1ptr[0]; cc.inv_x1 = 1.0f / cc.x1; cc.c49 = (4.0f / 9.0f) * cc.inv_x1;
    float s1a[4] = {0.f, 0.f, 0.f, 0.f};
    float s2a[4] = {0.f, 0.f, 0.f, 0.f};
    if (c < nchunks) {
        const int g0 = c * L_CHUNK;
        const int g1 = min(g0 + L_CHUNK, T);
        const int w0 = max(g0 - WARMUP, 0);
        float s = 0.0f; float pn, en, ps, pc;
        const float2* __restrict__ x2 = (const float2*)x;
        for (int t = w0; t < g0; ++t) { float2 xv = x2[t]; scan_step_fb(s, xv.x, xv.y, cc, pn, en, ps, pc); }
        float4* __restrict__ out4 = (float4*)out;
        for (int t = g0; t < g1; ++t) {
            float2 xv = x2[t];
            scan_step_fb(s, xv.x, xv.y, cc, pn, en, ps, pc);
            out4[t] = make_float4(pn, en, ps, pc);
            s_store[t] = s;
            s1a[0] += pn; s1a[1] += en; s1a[2] += ps; s1a[3] += pc;
            s2a[0] = fmaf(pn, pn, s2a[0]); s2a[1] = fmaf(en, en, s2a[1]);
            s2a[2] = fmaf(ps, ps, s2a[2]); s2a[3] = fmaf(pc, pc, s2a[3]);
        }
    }
    __shared__ float red[256];
    float vals[8] = {s1a[0], s1a[1], s1a[2], s1a[3], s2a[0], s2a[1], s2a[2], s2a[3]};
    for (int k = 0; k < 8; ++k) {
        red[threadIdx.x] = vals[k];
        __syncthreads();
        for (int off = 128; off > 0; off >>= 1) {
            if ((int)threadIdx.x < off) red[threadIdx.x] += red[threadIdx.x + off];
            __syncthreads();
        }
        if (threadIdx.x == 0) partials[blockIdx.x * 8 + k] = red[0];
        __syncthreads();
    }
}
__global__ __launch_bounds__(64) void finalize_fb(
        const float* __restrict__ partials, float* __restrict__ stats, int nblk, int T) {
    const int lane = threadIdx.x;
    float v[8] = {0.f, 0.f, 0.f, 0.f, 0.f, 0.f, 0.f, 0.f};
    for (int b = lane; b < nblk; b += 64)
        for (int k = 0; k < 8; ++k) v[k] += partials[b * 8 + k];
    #pragma unroll
    for (int k = 0; k < 8; ++k)
        for (int off = 32; off > 0; off >>= 1) v[k] += __shfl_down(v[k], off, 64);
    if (lane == 0) {
        const float invT = 1.0f / (float)T;
        for (int k = 0; k < 4; ++k) {
            float mu = v[k] * invT;
            float var = fmaxf(fmaf(-mu, mu, v[k + 4] * invT), 0.0f);
            stats[k] = mu;
            stats[4 + k] = (var > 0.0f) ? rsqrtf(var) : 0.0f;
        }
    }
}
__global__ __launch_bounds__(256) void normalize_fb(
        float* __restrict__ out, const float* __restrict__ stats, int T) {
    const int t = blockIdx.x * blockDim.x + threadIdx.x;
    if (t >= T) return;
    const float4 mu = *(const float4*)stats;
    const float4 is = *(const float4*)(stats + 4);
    float4* o4 = (float4*)out;
    float4 v = o4[t];
    v.x = (v.x - mu.x) * is.x; v.y = (v.y - mu.y) * is.y;
    v.z = (v.z - mu.z) * is.z; v.w = (v.w - mu.w) * is.w;
    o4[t] = v;
}
// -----------------------------------------------------------

extern "C" void kernel_launch(void* const* d_in, const int* in_sizes, int n_in,
                              void* d_out, int out_size, void* d_ws, size_t ws_size,
                              hipStream_t stream) {
    const float* x  = (const float*)d_in[0];
    const float* x1 = (const float*)d_in[1];
    const int T = in_sizes[0] / 2;

    float* out     = (float*)d_out;                // (T,4)
    float* s_store = out + 4 * (size_t)T;          // (T,)
    float* stats   = (float*)d_ws;                 // 8 floats

    const int C  = T / L_CHUNK;                    // chunks
    const int Cp = C + W_TILES;                    // padded columns
    const int nA = C / 64;                         // scan blocks (fast path)
    const int gBx = (Cp + 255) / 256;
    const int nB = gBx * 4;                        // featurize blocks

    float* pA = stats + 8;                         // nA*4
    float* pB = pA + 1024;                         // nB*4 (<=1040)
    size_t g4_off = 8 + 1024 + 1040;               // floats
    g4_off = (g4_off + 3) & ~(size_t)3;            // float4 align
    const size_t g4_floats = (size_t)64 * Cp * 4;  // 16.8 MB
    size_t pq_off = g4_off + g4_floats;
    const size_t need = (pq_off + 2 * (size_t)T) * sizeof(float);

    const bool fast = (T % L_CHUNK == 0) && (C % 64 == 0) && (T >= WARMUP) &&
                      (ws_size >= need);

    if (fast) {
        float4* G4     = (float4*)((float*)d_ws + g4_off);
        float4* pspc4  = (float4*)((float*)d_ws + pq_off);
        dim3 fg(gBx, 4);
        featurize2<<<fg, 256, 0, stream>>>(x, x1, G4, pB, Cp, T);
        scan_pipe<<<nA, 64, 0, stream>>>(G4, x1, pspc4, (float4*)s_store, pA, Cp);
        finalize_comb<<<1, 64, 0, stream>>>(pA, pB, stats, nA, nB, T);
        const int Thalf = T / 2;
        normalize_fused<<<(Thalf + 255) / 256, 256, 0, stream>>>(
            x, pspc4, stats, (float4*)out, Thalf);
    } else {
        float* partials = stats + 8;
        const int nchunks = (T + L_CHUNK - 1) / L_CHUNK;
        const int nblkA = (nchunks + 255) / 256;
        scan_kernel_fb<<<nblkA, 256, 0, stream>>>(x, x1, out, s_store, partials, T);
        finalize_fb<<<1, 64, 0, stream>>>(partials, stats, nblkA, T);
        normalize_fb<<<(T + 255) / 256, 256, 0, stream>>>(out, stats, T);
    }
}

// Round 4
// 196.609 us; speedup vs baseline: 1.7309x; 1.1965x over previous
//
#include <hip/hip_runtime.h>

// GR4J production-store scan, parallelized by contraction (W=2048 warm-up
// steps recover chunk-entry state; measured absmax 1.0 vs threshold 4.82).
//
// Round-4: register-rotation prefetch (no LDS, no DMA, no manual waitcnt).
//   featurize2 : LDS-transpose; coalesced x reads; (tp/x1, tn/x1) pairs in
//                G4[rowpair*Cp + col], 16 front pad columns of zeros.
//   scan_reg   : 1 chunk/thread, 64-thread blocks. 272 stages of 8 steps.
//                3 rotating register buffers (A,B,C), unroll-3: stage t
//                computes buf[t%3] then reloads it for stage t+3 ->
//                prefetch distance 2 stages (~700 cyc) with zero copies.
//                19-op 10-level step. Emits (ps,pc)+s, stats via shuffles.
//   finalize_comb + normalize_fused : unchanged from round 3.
// Fallback to the round-1 kernel if ws_size too small / odd shapes.

#define L_CHUNK 128
#define WARMUP  2048
#define W_TILES (WARMUP / L_CHUNK)            // 16
#define N_STAGE ((WARMUP + L_CHUNK) / 8)      // 272 stages of 8 steps
#define WU_STAGE (WARMUP / 8)                 // 256 warm-up stages

struct SC { float x1, x1sq, x1_2, c49; };

// one step from precomputed (tpx = tp/x1, tnx = tn/x1); ~19 VALU ops, 10-level chain
__device__ __forceinline__ void stepm(float& s, float tpx, float tnx, const SC c,
                                      float& ps_o, float& pc_o) {
    float a   = s * tpx;                         // r*tp
    float i   = fmaf(a, a - 1.0f, 1.0f);         // ~1/(1+a)
    float num = tpx * fmaf(-s, s, c.x1sq);       // x1*tp*(1-r^2)
    float w   = c.x1 - s;
    float dd  = tnx * w;                         // (1-r)*tn
    float jj  = fmaf(dd, dd - 1.0f, 1.0f);       // ~1/(1+dd)
    float mm  = (s * tnx) * (c.x1_2 - s);        // s*(2-r)*tn
    float t1  = fmaf(num, i, s);                 // s + p_s
    float s1  = fmaf(-mm, jj, t1);               // s + p_s - e_s
    float z = s1 * c.c49, z2 = z * z, v = z2 * z2;
    float th = fmaf(v, -0.25f, 1.0f);            // (1+v)^-1/4, 1st order
    float s2 = s1 * th;
    ps_o = num * i;
    pc_o = s1 - s2;
    s = s2;
}

// ---- featurize: coalesced read, LDS transpose, (tpx,tnx) pairs + pn/en stats ----
__global__ __launch_bounds__(256) void featurize2(
        const float* __restrict__ x, const float* __restrict__ x1p,
        float4* __restrict__ G4, float* __restrict__ partialsB, int Cp) {
    __shared__ float4 lx[16 * 65];                 // 16 cols x 64 rowpairs, +1 pad
    const int col0 = blockIdx.x * 16;
    const int tid  = threadIdx.x;
    const float x1 = x1p[0];
    const float inv = 1.0f / x1;
    float spn = 0.f, sen = 0.f, qpn = 0.f, qen = 0.f;
    const int cl  = tid & 15;
    const int rp0 = tid >> 4;

    if (col0 >= W_TILES) {
        const float4* __restrict__ x4 = (const float4*)x;
        const size_t base = (size_t)(col0 - W_TILES) * 64;   // float4 index
        #pragma unroll
        for (int k = 0; k < 4; ++k) {
            const int i = tid + 256 * k;
            lx[(i >> 6) * 65 + (i & 63)] = x4[base + i];
        }
        __syncthreads();
        #pragma unroll
        for (int k = 0; k < 4; ++k) {
            const int rp = rp0 + 16 * k;
            float4 xv = lx[cl * 65 + rp];          // (P,E,P,E) of 2 steps
            float d0 = xv.x - xv.y, d1 = xv.z - xv.w;
            float pn0 = fmaxf(d0, 0.f), en0 = fmaxf(-d0, 0.f);
            float pn1 = fmaxf(d1, 0.f), en1 = fmaxf(-d1, 0.f);
            float u0 = pn0 * inv, v0 = en0 * inv;
            float u1 = pn1 * inv, v1 = en1 * inv;
            float tpx0 = (u0 * fmaf(u0 * u0, -(1.f/3.f), 1.f)) * inv;
            float tnx0 = (v0 * fmaf(v0 * v0, -(1.f/3.f), 1.f)) * inv;
            float tpx1 = (u1 * fmaf(u1 * u1, -(1.f/3.f), 1.f)) * inv;
            float tnx1 = (v1 * fmaf(v1 * v1, -(1.f/3.f), 1.f)) * inv;
            G4[(size_t)rp * Cp + col0 + cl] = make_float4(tpx0, tnx0, tpx1, tnx1);
            spn += pn0 + pn1; sen += en0 + en1;
            qpn = fmaf(pn0, pn0, fmaf(pn1, pn1, qpn));
            qen = fmaf(en0, en0, fmaf(en1, en1, qen));
        }
    } else {                                       // all-pad block (block 0)
        const float4 z = make_float4(0.f, 0.f, 0.f, 0.f);
        #pragma unroll
        for (int k = 0; k < 4; ++k)
            G4[(size_t)(rp0 + 16 * k) * Cp + col0 + cl] = z;
    }

    __shared__ float red[256];
    float vals[4] = {spn, sen, qpn, qen};
    for (int k = 0; k < 4; ++k) {
        red[tid] = vals[k];
        __syncthreads();
        for (int off = 128; off > 0; off >>= 1) {
            if (tid < off) red[tid] += red[tid + off];
            __syncthreads();
        }
        if (tid == 0) partialsB[blockIdx.x * 4 + k] = red[0];
        __syncthreads();
    }
}

// ---- the register-pipelined scan ----
__global__ __launch_bounds__(64, 1) void scan_reg(
        const float4* __restrict__ G4, const float* __restrict__ x1p,
        float4* __restrict__ pspc4, float4* __restrict__ s4,
        float* __restrict__ partialsA, int Cp) {
    const int lane  = threadIdx.x;
    const int chunk = blockIdx.x * 64 + lane;
    SC cc;
    cc.x1 = x1p[0]; cc.x1sq = cc.x1 * cc.x1; cc.x1_2 = 2.0f * cc.x1;
    cc.c49 = (4.0f / 9.0f) / cc.x1;

    const float4* gbase = G4 + (size_t)blockIdx.x * 64 + lane;
    const size_t cp = (size_t)Cp;

    auto ldst = [&](float4 (&q)[4], int st) {
        const int j = st >> 4, sg = st & 15;
        const float4* g = gbase + (size_t)(4 * sg) * cp + j;
        #pragma unroll
        for (int u = 0; u < 4; ++u) q[u] = g[(size_t)u * cp];
    };

    float s = 0.0f;
    float acc[4] = {0.f, 0.f, 0.f, 0.f};

    auto do_stage = [&](float4 (&q)[4], int t) {
        float psv[8], pcv[8], sv[8];
        #pragma unroll
        for (int u = 0; u < 4; ++u) {
            stepm(s, q[u].x, q[u].y, cc, psv[2*u], pcv[2*u]);     sv[2*u]   = s;
            stepm(s, q[u].z, q[u].w, cc, psv[2*u+1], pcv[2*u+1]); sv[2*u+1] = s;
        }
        if (t >= WU_STAGE) {                       // main phase: outputs + stats
            #pragma unroll
            for (int u = 0; u < 8; ++u) {
                acc[0] += psv[u]; acc[1] += pcv[u];
                acc[2] = fmaf(psv[u], psv[u], acc[2]);
                acc[3] = fmaf(pcv[u], pcv[u], acc[3]);
            }
            const int mb = t - WU_STAGE;
            const size_t pb = (size_t)chunk * 64 + 4 * mb;
            #pragma unroll
            for (int k = 0; k < 4; ++k)
                pspc4[pb + k] = make_float4(psv[2*k], pcv[2*k], psv[2*k+1], pcv[2*k+1]);
            const size_t sb = (size_t)chunk * 32 + 2 * mb;
            s4[sb]     = make_float4(sv[0], sv[1], sv[2], sv[3]);
            s4[sb + 1] = make_float4(sv[4], sv[5], sv[6], sv[7]);
        }
        const int tn = t + 3;                      // prefetch distance 2 stages
        if (tn < N_STAGE) ldst(q, tn);             // WAR: loads issue after q's last read
    };

    float4 A[4], B[4], C[4];
    ldst(A, 0); ldst(B, 1); ldst(C, 2);

    int t = 0;
    for (int tb = 0; tb < N_STAGE / 3; ++tb) {     // 90 trips -> stages 0..269
        do_stage(A, t);
        do_stage(B, t + 1);
        do_stage(C, t + 2);
        t += 3;
    }
    do_stage(A, t);                                // stage 270
    do_stage(B, t + 1);                            // stage 271

    // ---- wave reduction (block == 1 wave) ----
    #pragma unroll
    for (int k = 0; k < 4; ++k) {
        float v = acc[k];
        #pragma unroll
        for (int off = 32; off > 0; off >>= 1) v += __shfl_down(v, off, 64);
        if (lane == 0) partialsA[blockIdx.x * 4 + k] = v;
    }
}

__global__ __launch_bounds__(64) void finalize_comb(
        const float* __restrict__ pA, const float* __restrict__ pB,
        float* __restrict__ stats, int nA, int nB, int T) {
    const int lane = threadIdx.x;
    float v[8] = {0.f, 0.f, 0.f, 0.f, 0.f, 0.f, 0.f, 0.f};
    for (int b = lane; b < nA; b += 64) {          // scan: ps,pc
        v[2] += pA[b * 4 + 0]; v[3] += pA[b * 4 + 1];
        v[6] += pA[b * 4 + 2]; v[7] += pA[b * 4 + 3];
    }
    for (int b = lane; b < nB; b += 64) {          // featurize: pn,en
        v[0] += pB[b * 4 + 0]; v[1] += pB[b * 4 + 1];
        v[4] += pB[b * 4 + 2]; v[5] += pB[b * 4 + 3];
    }
    #pragma unroll
    for (int k = 0; k < 8; ++k) {
        #pragma unroll
        for (int off = 32; off > 0; off >>= 1) v[k] += __shfl_down(v[k], off, 64);
    }
    if (lane == 0) {
        const float invT = 1.0f / (float)T;
        #pragma unroll
        for (int k = 0; k < 4; ++k) {
            float mu  = v[k] * invT;
            float var = fmaxf(fmaf(-mu, mu, v[k + 4] * invT), 0.0f);
            stats[k]     = mu;
            stats[4 + k] = (var > 0.0f) ? rsqrtf(var) : 0.0f;
        }
    }
}

__global__ __launch_bounds__(256) void normalize_fused(
        const float* __restrict__ x, const float4* __restrict__ pspc4,
        const float* __restrict__ stats, float4* __restrict__ out4, int Thalf) {
    const int i = blockIdx.x * 256 + threadIdx.x;
    if (i >= Thalf) return;
    const float4 mu = ((const float4*)stats)[0];
    const float4 is = ((const float4*)stats)[1];
    float4 xv = ((const float4*)x)[i];
    float4 pq = pspc4[i];
    float d0 = xv.x - xv.y, d1 = xv.z - xv.w;
    out4[2 * i] = make_float4((fmaxf(d0, 0.f) - mu.x) * is.x,
                              (fmaxf(-d0, 0.f) - mu.y) * is.y,
                              (pq.x - mu.z) * is.z,
                              (pq.y - mu.w) * is.w);
    out4[2 * i + 1] = make_float4((fmaxf(d1, 0.f) - mu.x) * is.x,
                                  (fmaxf(-d1, 0.f) - mu.y) * is.y,
                                  (pq.z - mu.z) * is.z,
                                  (pq.w - mu.w) * is.w);
}

// ---------------- round-1 fallback (proven) ----------------
__device__ __forceinline__ float inv1p_fb(float a) {
    float i1 = 1.0f - a;
    float i2 = fmaf(-a, i1, 1.0f);
    return fmaf(-a, i2, 1.0f);
}
struct SCfb { float x1, inv_x1, c49; };
__device__ __forceinline__ void scan_step_fb(float& s, float P, float E, const SCfb c,
                                             float& pn, float& en, float& ps, float& pc) {
    float d = P - E;
    float pn_ = fmaxf(d, 0.0f), en_ = fmaxf(-d, 0.0f);
    float up = pn_ * c.inv_x1;
    float tp = up * fmaf(up * up, -(1.0f / 3.0f), 1.0f);
    float un = en_ * c.inv_x1;
    float tn = un * fmaf(un * un, -(1.0f / 3.0f), 1.0f);
    float r = s * c.inv_x1;
    float ps_ = (tp * c.x1) * fmaf(-r, r, 1.0f) * inv1p_fb(r * tp);
    float es_ = (s * (2.0f - r)) * tn * inv1p_fb((1.0f - r) * tn);
    float s1 = s + ps_ - es_;
    float z = s1 * c.c49, z2 = z * z, v = z2 * z2;
    float t = fmaf(v, fmaf(v, 0.15625f, -0.25f), 1.0f);
    float s2 = s1 * t;
    pn = pn_; en = en_; ps = ps_; pc = s1 - s2; s = s2;
}
__global__ __launch_bounds__(256) void scan_kernel_fb(
        const float* __restrict__ x, const float* __restrict__ x1ptr,
        float* __restrict__ out, float* __restrict__ s_store,
        float* __restrict__ partials, int T) {
    const int c = blockIdx.x * blockDim.x + threadIdx.x;
    const int nchunks = (T + L_CHUNK - 1) / L_CHUNK;
    SCfb cc; cc.x1 = x1ptr[0]; cc.inv_x1 = 1.0f / cc.x1; cc.c49 = (4.0f / 9.0f) * cc.inv_x1;
    float s1a[4] = {0.f, 0.f, 0.f, 0.f};
    float s2a[4] = {0.f, 0.f, 0.f, 0.f};
    if (c < nchunks) {
        const int g0 = c * L_CHUNK;
        const int g1 = min(g0 + L_CHUNK, T);
        const int w0 = max(g0 - WARMUP, 0);
        float s = 0.0f; float pn, en, ps, pc;
        const float2* __restrict__ x2 = (const float2*)x;
        for (int t = w0; t < g0; ++t) { float2 xv = x2[t]; scan_step_fb(s, xv.x, xv.y, cc, pn, en, ps, pc); }
        float4* __restrict__ out4 = (float4*)out;
        for (int t = g0; t < g1; ++t) {
            float2 xv = x2[t];
            scan_step_fb(s, xv.x, xv.y, cc, pn, en, ps, pc);
            out4[t] = make_float4(pn, en, ps, pc);
            s_store[t] = s;
            s1a[0] += pn; s1a[1] += en; s1a[2] += ps; s1a[3] += pc;
            s2a[0] = fmaf(pn, pn, s2a[0]); s2a[1] = fmaf(en, en, s2a[1]);
            s2a[2] = fmaf(ps, ps, s2a[2]); s2a[3] = fmaf(pc, pc, s2a[3]);
        }
    }
    __shared__ float red[256];
    float vals[8] = {s1a[0], s1a[1], s1a[2], s1a[3], s2a[0], s2a[1], s2a[2], s2a[3]};
    for (int k = 0; k < 8; ++k) {
        red[threadIdx.x] = vals[k];
        __syncthreads();
        for (int off = 128; off > 0; off >>= 1) {
            if ((int)threadIdx.x < off) red[threadIdx.x] += red[threadIdx.x + off];
            __syncthreads();
        }
        if (threadIdx.x == 0) partials[blockIdx.x * 8 + k] = red[0];
        __syncthreads();
    }
}
__global__ __launch_bounds__(64) void finalize_fb(
        const float* __restrict__ partials, float* __restrict__ stats, int nblk, int T) {
    const int lane = threadIdx.x;
    float v[8] = {0.f, 0.f, 0.f, 0.f, 0.f, 0.f, 0.f, 0.f};
    for (int b = lane; b < nblk; b += 64)
        for (int k = 0; k < 8; ++k) v[k] += partials[b * 8 + k];
    #pragma unroll
    for (int k = 0; k < 8; ++k)
        for (int off = 32; off > 0; off >>= 1) v[k] += __shfl_down(v[k], off, 64);
    if (lane == 0) {
        const float invT = 1.0f / (float)T;
        for (int k = 0; k < 4; ++k) {
            float mu = v[k] * invT;
            float var = fmaxf(fmaf(-mu, mu, v[k + 4] * invT), 0.0f);
            stats[k] = mu;
            stats[4 + k] = (var > 0.0f) ? rsqrtf(var) : 0.0f;
        }
    }
}
__global__ __launch_bounds__(256) void normalize_fb(
        float* __restrict__ out, const float* __restrict__ stats, int T) {
    const int t = blockIdx.x * blockDim.x + threadIdx.x;
    if (t >= T) return;
    const float4 mu = *(const float4*)stats;
    const float4 is = *(const float4*)(stats + 4);
    float4* o4 = (float4*)out;
    float4 v = o4[t];
    v.x = (v.x - mu.x) * is.x; v.y = (v.y - mu.y) * is.y;
    v.z = (v.z - mu.z) * is.z; v.w = (v.w - mu.w) * is.w;
    o4[t] = v;
}
// -----------------------------------------------------------

extern "C" void kernel_launch(void* const* d_in, const int* in_sizes, int n_in,
                              void* d_out, int out_size, void* d_ws, size_t ws_size,
                              hipStream_t stream) {
    const float* x  = (const float*)d_in[0];
    const float* x1 = (const float*)d_in[1];
    const int T = in_sizes[0] / 2;

    float* out     = (float*)d_out;                // (T,4)
    float* s_store = out + 4 * (size_t)T;          // (T,)
    float* stats   = (float*)d_ws;                 // 8 floats

    const int C  = T / L_CHUNK;                    // chunks
    const int Cp = C + W_TILES;                    // padded columns
    const int nA = C / 64;                         // scan blocks (fast path)
    const int nB = Cp / 16;                        // featurize blocks

    float* pA = stats + 8;                         // nA*4 (<=1024)
    float* pB = pA + 1024;                         // nB*4 (<=4100)
    size_t g4_off = 8 + 1024 + 4100;               // floats
    g4_off = (g4_off + 3) & ~(size_t)3;            // float4 align
    const size_t g4_floats = (size_t)64 * Cp * 4;  // 16.8 MB
    size_t pq_off = g4_off + g4_floats;
    const size_t need = (pq_off + 2 * (size_t)T) * sizeof(float);

    const bool fast = (T % L_CHUNK == 0) && (C % 64 == 0) && (Cp % 16 == 0) &&
                      (T >= WARMUP) && (ws_size >= need);

    if (fast) {
        float4* G4     = (float4*)((float*)d_ws + g4_off);
        float4* pspc4  = (float4*)((float*)d_ws + pq_off);
        featurize2<<<nB, 256, 0, stream>>>(x, x1, G4, pB, Cp);
        scan_reg<<<nA, 64, 0, stream>>>(G4, x1, pspc4, (float4*)s_store, pA, Cp);
        finalize_comb<<<1, 64, 0, stream>>>(pA, pB, stats, nA, nB, T);
        const int Thalf = T / 2;
        normalize_fused<<<(Thalf + 255) / 256, 256, 0, stream>>>(
            x, pspc4, stats, (float4*)out, Thalf);
    } else {
        float* partials = stats + 8;
        const int nchunks = (T + L_CHUNK - 1) / L_CHUNK;
        const int nblkA = (nchunks + 255) / 256;
        scan_kernel_fb<<<nblkA, 256, 0, stream>>>(x, x1, out, s_store, partials, T);
        finalize_fb<<<1, 64, 0, stream>>>(partials, stats, nblkA, T);
        normalize_fb<<<(T + 255) / 256, 256, 0, stream>>>(out, stats, T);
    }
}